// Round 1
// 587.143 us; speedup vs baseline: 1.0614x; 1.0614x over previous
//
#include <hip/hip_runtime.h>
#include <math.h>

#define DEV __device__ __forceinline__

DEV float gelu_exact(float v) {
    return 0.5f * v * (1.0f + erff(v * 0.7071067811865476f));
}

typedef __attribute__((ext_vector_type(8))) short bf16x8;
typedef __attribute__((ext_vector_type(4))) float f32x4;

DEV short f2b(float f) {
    unsigned u = __builtin_bit_cast(unsigned, f);
    unsigned r = (u + 0x7fffu + ((u >> 16) & 1u)) >> 16;
    return (short)r;
}

// ---------------------------------------------------------------------------
// K1: tiny MLPs -> conv weights sw[96][125] (f32) and transposed mix matrix
// Mtt[gw=96][fv=96] in bf16 (pre-converted so ek's A-frags are 16B vector loads).
// ---------------------------------------------------------------------------
__global__ __launch_bounds__(256) void wk(
    const float* __restrict__ spatial, const float* __restrict__ spherical,
    const float* __restrict__ bw1, const float* __restrict__ bb1,
    const float* __restrict__ bw2, const float* __restrict__ bb2,
    const float* __restrict__ bw3,
    const float* __restrict__ fw1, const float* __restrict__ fb1,
    const float* __restrict__ fw2, const float* __restrict__ fb2,
    const float* __restrict__ fw3,
    float* __restrict__ sw, unsigned short* __restrict__ Mtt) {
    const int i = blockIdx.x * 256 + threadIdx.x;
    if (i < 1500) {
        const float a = spatial[2 * i], b = spatial[2 * i + 1];
        float ft[14];
        ft[0] = a; ft[1] = b;
        ft[2] = a * a; ft[3] = a * b; ft[4] = b * a; ft[5] = b * b;
#pragma unroll
        for (int k = 0; k < 4; ++k) {
            ft[6 + 2 * k] = ft[2 + k] * a;
            ft[7 + 2 * k] = ft[2 + k] * b;
        }
        float h1[8], h2[8];
#pragma unroll
        for (int j = 0; j < 8; ++j) {
            float s = bb1[j];
#pragma unroll
            for (int k = 0; k < 14; ++k) s = fmaf(bw1[j * 14 + k], ft[k], s);
            h1[j] = gelu_exact(s);
        }
#pragma unroll
        for (int j = 0; j < 8; ++j) {
            float s = bb2[j];
#pragma unroll
            for (int k = 0; k < 8; ++k) s = fmaf(bw2[j * 8 + k], h1[k], s);
            h2[j] = gelu_exact(s);
        }
        const int o = i / 12, v = i % 12;
#pragma unroll
        for (int c = 0; c < 8; ++c) {
            float s = 0.f;
#pragma unroll
            for (int k = 0; k < 8; ++k) s = fmaf(bw3[c * 8 + k], h2[k], s);
            sw[(c * 12 + v) * 125 + o] = s;   // channel ch = cin*12+v, tap o = A*25+B*5+C
        }
    } else if (i < 1644) {
        const int r = i - 1500;
        const float s0 = spherical[r];
        float ft[3];
        ft[0] = s0; ft[1] = s0 * s0; ft[2] = s0 * s0 * s0;
        float h1[8], h2[8];
#pragma unroll
        for (int j = 0; j < 8; ++j) {
            float s = fb1[j];
#pragma unroll
            for (int k = 0; k < 3; ++k) s = fmaf(fw1[j * 3 + k], ft[k], s);
            h1[j] = gelu_exact(s);
        }
#pragma unroll
        for (int j = 0; j < 8; ++j) {
            float s = fb2[j];
#pragma unroll
            for (int k = 0; k < 8; ++k) s = fmaf(fw2[j * 8 + k], h1[k], s);
            h2[j] = gelu_exact(s);
        }
        const int v = r / 12, w = r % 12;     // spherical row = (v, w)
#pragma unroll
        for (int c = 0; c < 64; ++c) {        // c = f*8 + g
            float s = 0.f;
#pragma unroll
            for (int k = 0; k < 8; ++k) s = fmaf(fw3[c * 8 + k], h2[k], s);
            const int f = c >> 3, g = c & 7;
            // Mtt[gw][fv] = fw[g,f,v,w] as bf16; gw = g*12+w, fv = f*12+v
            Mtt[(g * 12 + w) * 96 + f * 12 + v] = (unsigned short)f2b(s);
        }
    }
}

// ---------------------------------------------------------------------------
// K2: depthwise 5x5x5 conv, SAME/zero pad.  One block = 1 (b,ch), tile 64x8x8.
// x-tile (12z x 12y x 64x + zero pads) staged in LDS once (coalesced float4),
// inner loop is pure {3x ds_read_b128 + FMA} - no shuffles, no branches.
// LDS row pitch 80 floats; 16B-window XOR swizzle s=(row>>2)&3 spreads the
// 8xg x 4yg x 8zg read pattern to the 8-lane/window bank floor.
// Thread tile: 8x * 2y * 1z = 16 outputs.
// ---------------------------------------------------------------------------
#define CPITCH 80
__global__ __launch_bounds__(256) void ck(const float* __restrict__ x,
                                          const float* __restrict__ sw,
                                          float* __restrict__ y) {
    __shared__ float lds[12 * 12 * CPITCH];     // 46080 B
    const int ch = blockIdx.y, b = blockIdx.z;
    const int ty = (blockIdx.x & 7) << 3;
    const int tz = (blockIdx.x >> 3) << 3;
    const int t = threadIdx.x;
    const long cb = (long)(b * 96 + ch) << 18; // *262144
    const float* __restrict__ xb = x + cb;
    float* __restrict__ yb = y + cb;
    const float* __restrict__ w = sw + ch * 125;  // uniform -> scalar loads

    // ---- stage: 144 rows (12z x 12y), 16 lanes per row, 9 passes ----------
    {
        const int l16 = t & 15;
        const int rq = t >> 4;
#pragma unroll
        for (int pass = 0; pass < 9; ++pass) {
            const int r = rq + (pass << 4);
            const int zi = r / 12, yi = r % 12;
            const int zz = tz + zi - 2, yy = ty + yi - 2;
            float4 v = {0.f, 0.f, 0.f, 0.f};
            if (zz >= 0 && zz < 64 && yy >= 0 && yy < 64)
                v = *(const float4*)(xb + (zz << 12) + (yy << 6) + (l16 << 2));
            const int s = (r >> 2) & 3;
            float* rp = lds + r * CPITCH;
            // data occupies pad-indices [2..66); lane covers [2+4*l16, +4)
            float* p0 = rp + (((l16 ^ s) << 2) + 2);        // window l16, off 2
            p0[0] = v.x; p0[1] = v.y;
            float* p1 = rp + (((l16 + 1) ^ s) << 2);        // window l16+1, off 0
            p1[0] = v.z; p1[1] = v.w;
            if (l16 == 0) {        // left zero pad: floats 0,1 (window 0, off 0)
                float* p = rp + ((0 ^ s) << 2);
                p[0] = 0.f; p[1] = 0.f;
            }
            if (l16 == 15) {       // right zero pad: floats 66,67 (window 16, off 2)
                float* p = rp + (((16 ^ s) << 2) + 2);
                p[0] = 0.f; p[1] = 0.f;
            }
        }
    }
    __syncthreads();

    // ---- conv ------------------------------------------------------------
    const int xg = t & 7;          // x0 = 8*xg
    const int yg = (t >> 3) & 3;   // y0 = 2*yg
    const int zg = t >> 5;         // z  = zg (0..7)
    const int w0 = xg << 1;        // base 16B-window of this thread's x-window

    float acc[2][8];
#pragma unroll
    for (int i = 0; i < 2; ++i)
#pragma unroll
        for (int j = 0; j < 8; ++j) acc[i][j] = 0.f;

#pragma unroll
    for (int hz = 0; hz < 5; ++hz) {           // A = hz (z tap)
#pragma unroll
        for (int hy = 0; hy < 6; ++hy) {       // hy = dy + B
            const int row = (zg + hz) * 12 + (yg << 1) + hy;
            const int s = (row >> 2) & 3;
            const float* rp = lds + row * CPITCH;
            const float4 fa = *(const float4*)(rp + (((w0 + 0) ^ s) << 2));
            const float4 fb = *(const float4*)(rp + (((w0 + 1) ^ s) << 2));
            const float4 fc = *(const float4*)(rp + (((w0 + 2) ^ s) << 2));
            const float f[12] = {fa.x, fa.y, fa.z, fa.w, fb.x, fb.y, fb.z, fb.w,
                                 fc.x, fc.y, fc.z, fc.w};
#pragma unroll
            for (int dy = 0; dy < 2; ++dy) {
                const int B = hy - dy;
                if (B < 0 || B > 4) continue;      // folded at compile time
                const float* wr = w + (hz * 5 + B) * 5;
#pragma unroll
                for (int C = 0; C < 5; ++C) {
                    const float wv = wr[C];
#pragma unroll
                    for (int dx = 0; dx < 8; ++dx)
                        acc[dy][dx] = fmaf(f[C + dx], wv, acc[dy][dx]);
                }
            }
        }
    }

    // ---- store 16 outputs ------------------------------------------------
    const int zo = tz + zg;
    const int xo = xg << 3;
#pragma unroll
    for (int dy = 0; dy < 2; ++dy) {
        const int yo = ty + (yg << 1) + dy;
        float* op = yb + (zo << 12) + (yo << 6) + xo;
        float4 o0 = {acc[dy][0], acc[dy][1], acc[dy][2], acc[dy][3]};
        float4 o1 = {acc[dy][4], acc[dy][5], acc[dy][6], acc[dy][7]};
        *(float4*)(op) = o0;
        *(float4*)(op + 4) = o1;
    }
}

// ---------------------------------------------------------------------------
// K3: in-place per-point 96->96 mix + bias as bf16 MFMA GEMM.
// Block = 128 pts: y[96][128] f32 staged to LDS with coalesced float4 loads;
// B-frags built from LDS (f2b), A-frags are single 16B loads of bf16 Mtt.
// All io reads complete before the barrier; stores hit only this block's pts
// -> in-place safe as before.
// ---------------------------------------------------------------------------
#define EPITCH 132
__global__ __launch_bounds__(256) void ek(float* __restrict__ io,
                                          const unsigned short* __restrict__ Mtt,
                                          const float* __restrict__ bias) {
    __shared__ float yt[96 * EPITCH];           // 50688 B
    const int t = threadIdx.x;
    const long b_off = ((long)blockIdx.y * 96) << 18;
    const int pt0 = blockIdx.x << 7;            // this block's 128 pts

    // ---- stage y[96][128] -> LDS (8 rows per pass, 12 passes) ------------
    {
        const int l32 = t & 31;
        const int r8 = t >> 5;
#pragma unroll
        for (int pass = 0; pass < 12; ++pass) {
            const int fv = r8 + (pass << 3);
            const float4 v = *(const float4*)(io + b_off + ((long)fv << 18) + pt0 + (l32 << 2));
            *(float4*)(yt + fv * EPITCH + (l32 << 2)) = v;
        }
    }
    __syncthreads();

    const int lane = t & 63;
    const int wv = t >> 6;                     // wave id 0..3
    const int l15 = lane & 15, quad = lane >> 4;
    const int ptl = wv << 5;                   // wave's 32 pts within tile

    // B-frags: y (2 n-tiles x 3 ksteps), B[k=quad*8+j -> fv][n=l15 -> pt]
    bf16x8 Bf[2][3];
#pragma unroll
    for (int nt = 0; nt < 2; ++nt)
#pragma unroll
        for (int ks = 0; ks < 3; ++ks)
#pragma unroll
            for (int j = 0; j < 8; ++j) {
                const int fv = ks * 32 + quad * 8 + j;
                Bf[nt][ks][j] = f2b(yt[fv * EPITCH + ptl + nt * 16 + l15]);
            }

    const long po = b_off + pt0 + ptl;
#pragma unroll
    for (int mt = 0; mt < 6; ++mt) {
        bf16x8 Af[3];                          // A[m=l15 -> gw][k=quad*8+j -> fv]
#pragma unroll
        for (int ks = 0; ks < 3; ++ks)
            Af[ks] = *(const bf16x8*)(Mtt + (mt * 16 + l15) * 96 + ks * 32 + quad * 8);
#pragma unroll
        for (int nt = 0; nt < 2; ++nt) {
            f32x4 c = {0.f, 0.f, 0.f, 0.f};
#pragma unroll
            for (int ks = 0; ks < 3; ++ks)
                c = __builtin_amdgcn_mfma_f32_16x16x32_bf16(Af[ks], Bf[nt][ks], c, 0, 0, 0);
#pragma unroll
            for (int r = 0; r < 4; ++r) {
                const int gw = mt * 16 + quad * 4 + r;
                io[po + ((long)gw << 18) + nt * 16 + l15] = c[r] + bias[gw / 12];
            }
        }
    }
}

// ---------------------------------------------------------------------------
extern "C" void kernel_launch(void* const* d_in, const int* in_sizes, int n_in,
                              void* d_out, int out_size, void* d_ws, size_t ws_size,
                              hipStream_t stream) {
    const float* x        = (const float*)d_in[0];
    const float* spatial  = (const float*)d_in[1];
    const float* spherical= (const float*)d_in[2];
    const float* bw1 = (const float*)d_in[3];
    const float* bb1 = (const float*)d_in[4];
    const float* bw2 = (const float*)d_in[5];
    const float* bb2 = (const float*)d_in[6];
    const float* bw3 = (const float*)d_in[7];
    const float* fw1 = (const float*)d_in[8];
    const float* fb1 = (const float*)d_in[9];
    const float* fw2 = (const float*)d_in[10];
    const float* fb2 = (const float*)d_in[11];
    const float* fw3 = (const float*)d_in[12];
    const float* bias = (const float*)d_in[13];

    float* sw = (float*)d_ws;                                   // 12000 floats
    unsigned short* Mtt = (unsigned short*)((char*)d_ws + 48128); // 9216 bf16
    float* out = (float*)d_out;          // also conv staging buffer

    hipLaunchKernelGGL(wk, dim3(7), dim3(256), 0, stream,
                       spatial, spherical, bw1, bb1, bw2, bb2, bw3,
                       fw1, fb1, fw2, fb2, fw3, sw, Mtt);
    hipLaunchKernelGGL(ck, dim3(64, 96, 2), dim3(256), 0, stream, x, sw, out);
    hipLaunchKernelGGL(ek, dim3(2048, 2, 1), dim3(256), 0, stream, out, Mtt, bias);
    (void)in_sizes; (void)n_in; (void)out_size; (void)ws_size;
}

// Round 2
// 585.200 us; speedup vs baseline: 1.0649x; 1.0033x over previous
//
#include <hip/hip_runtime.h>
#include <math.h>

#define DEV __device__ __forceinline__

DEV float gelu_exact(float v) {
    return 0.5f * v * (1.0f + erff(v * 0.7071067811865476f));
}

typedef __attribute__((ext_vector_type(8))) short bf16x8;
typedef __attribute__((ext_vector_type(4))) float f32x4;

DEV short f2b(float f) {
    unsigned u = __builtin_bit_cast(unsigned, f);
    unsigned r = (u + 0x7fffu + ((u >> 16) & 1u)) >> 16;
    return (short)r;
}

// ---------------------------------------------------------------------------
// K1: tiny MLPs -> conv weights sw[96][125] (f32) and transposed mix matrix
// Mtt[gw=96][fv=96] in bf16 (so ek's A-frags are single 16B vector loads).
// ---------------------------------------------------------------------------
__global__ __launch_bounds__(256) void wk(
    const float* __restrict__ spatial, const float* __restrict__ spherical,
    const float* __restrict__ bw1, const float* __restrict__ bb1,
    const float* __restrict__ bw2, const float* __restrict__ bb2,
    const float* __restrict__ bw3,
    const float* __restrict__ fw1, const float* __restrict__ fb1,
    const float* __restrict__ fw2, const float* __restrict__ fb2,
    const float* __restrict__ fw3,
    float* __restrict__ sw, unsigned short* __restrict__ Mtt) {
    const int i = blockIdx.x * 256 + threadIdx.x;
    if (i < 1500) {
        const float a = spatial[2 * i], b = spatial[2 * i + 1];
        float ft[14];
        ft[0] = a; ft[1] = b;
        ft[2] = a * a; ft[3] = a * b; ft[4] = b * a; ft[5] = b * b;
#pragma unroll
        for (int k = 0; k < 4; ++k) {
            ft[6 + 2 * k] = ft[2 + k] * a;
            ft[7 + 2 * k] = ft[2 + k] * b;
        }
        float h1[8], h2[8];
#pragma unroll
        for (int j = 0; j < 8; ++j) {
            float s = bb1[j];
#pragma unroll
            for (int k = 0; k < 14; ++k) s = fmaf(bw1[j * 14 + k], ft[k], s);
            h1[j] = gelu_exact(s);
        }
#pragma unroll
        for (int j = 0; j < 8; ++j) {
            float s = bb2[j];
#pragma unroll
            for (int k = 0; k < 8; ++k) s = fmaf(bw2[j * 8 + k], h1[k], s);
            h2[j] = gelu_exact(s);
        }
        const int o = i / 12, v = i % 12;
#pragma unroll
        for (int c = 0; c < 8; ++c) {
            float s = 0.f;
#pragma unroll
            for (int k = 0; k < 8; ++k) s = fmaf(bw3[c * 8 + k], h2[k], s);
            sw[(c * 12 + v) * 125 + o] = s;   // channel ch = cin*12+v, tap o = A*25+B*5+C
        }
    } else if (i < 1644) {
        const int r = i - 1500;
        const float s0 = spherical[r];
        float ft[3];
        ft[0] = s0; ft[1] = s0 * s0; ft[2] = s0 * s0 * s0;
        float h1[8], h2[8];
#pragma unroll
        for (int j = 0; j < 8; ++j) {
            float s = fb1[j];
#pragma unroll
            for (int k = 0; k < 3; ++k) s = fmaf(fw1[j * 3 + k], ft[k], s);
            h1[j] = gelu_exact(s);
        }
#pragma unroll
        for (int j = 0; j < 8; ++j) {
            float s = fb2[j];
#pragma unroll
            for (int k = 0; k < 8; ++k) s = fmaf(fw2[j * 8 + k], h1[k], s);
            h2[j] = gelu_exact(s);
        }
        const int v = r / 12, w = r % 12;     // spherical row = (v, w)
#pragma unroll
        for (int c = 0; c < 64; ++c) {        // c = f*8 + g
            float s = 0.f;
#pragma unroll
            for (int k = 0; k < 8; ++k) s = fmaf(fw3[c * 8 + k], h2[k], s);
            const int f = c >> 3, g = c & 7;
            Mtt[(g * 12 + w) * 96 + f * 12 + v] = (unsigned short)f2b(s);
        }
    }
}

// ---------------------------------------------------------------------------
// K2: depthwise 5x5x5 conv, SAME/zero pad.  One block = 1 (b,ch), tile 64x8x8.
// LDS layout: 144 rows (12z x 12y); row holds 68 floats (x=-2..65) mapped by
// off(f) = f + 4*(f>>5)  (4-float pad after every 8 windows) -> pitch 76.
// Bank math per wave-instruction: start = 8xg+4(xg>>2)+24yg+16zl mod 32 ->
// every bank hit exactly 8x = ds_read_b128 structural floor (0 conflicts).
// All conv reads: per-thread base pointer + compile-time offset (0 addr VALU).
// Thread tile: 8x * 2y * 1z = 16 outputs.
// ---------------------------------------------------------------------------
#define CPITCH 76
#define WOFF(wn) ((((wn) << 2) + (((wn) >> 3) << 2)))
__global__ __launch_bounds__(256) void ck(const float* __restrict__ x,
                                          const float* __restrict__ sw,
                                          float* __restrict__ y) {
    __shared__ float lds[144 * CPITCH];         // 43776 B
    const int ch = blockIdx.y, b = blockIdx.z;
    const int ty = (blockIdx.x & 7) << 3;
    const int tz = (blockIdx.x >> 3) << 3;
    const int t = threadIdx.x;
    const long cb = (long)(b * 96 + ch) << 18; // *262144
    const float* __restrict__ xb = x + cb;
    float* __restrict__ yb = y + cb;
    const float* __restrict__ w = sw + ch * 125;  // uniform -> scalar loads

    // ---- stage: 144 rows, 16 lanes/row load 4 floats each -----------------
    {
        const int l16 = t & 15;
        const int rq = t >> 4;
        const int o1 = (l16 << 2) + 2 + ((l16 >> 3) << 2);          // off(4*l16+2)
        const int o2 = (l16 << 2) + 4 + ((((l16 + 1) >> 3)) << 2);  // off(4*l16+4)
#pragma unroll
        for (int pass = 0; pass < 9; ++pass) {
            const int r = rq + (pass << 4);
            const int zi = r / 12, yi = r % 12;
            const int zz = tz + zi - 2, yy = ty + yi - 2;
            float4 v = {0.f, 0.f, 0.f, 0.f};
            if (zz >= 0 && zz < 64 && yy >= 0 && yy < 64)
                v = *(const float4*)(xb + (zz << 12) + (yy << 6) + (l16 << 2));
            float* rp = lds + r * CPITCH;
            rp[o1] = v.x; rp[o1 + 1] = v.y;
            rp[o2] = v.z; rp[o2 + 1] = v.w;
            if (l16 == 0)  { rp[0] = 0.f;  rp[1] = 0.f; }   // x=-2,-1
            if (l16 == 15) { rp[74] = 0.f; rp[75] = 0.f; }  // x=64,65
        }
    }
    __syncthreads();

    // ---- conv ------------------------------------------------------------
    const int xg = t & 7;          // x0 = 8*xg
    const int yg = (t >> 3) & 3;   // y0 = 2*yg
    const int zg = t >> 5;         // z  = zg
    const int rb = (zg * 12 + (yg << 1)) * CPITCH;
    const float* p0 = lds + rb + WOFF(2 * xg);
    const float* p1 = lds + rb + WOFF(2 * xg + 1);
    const float* p2 = lds + rb + WOFF(2 * xg + 2);

    float acc[2][8];
#pragma unroll
    for (int i = 0; i < 2; ++i)
#pragma unroll
        for (int j = 0; j < 8; ++j) acc[i][j] = 0.f;

#pragma unroll
    for (int hz = 0; hz < 5; ++hz) {           // A = hz (z tap)
#pragma unroll
        for (int hy = 0; hy < 6; ++hy) {       // hy = dy + B
            const int ro = (hz * 12 + hy) * CPITCH;   // compile-time -> imm offset
            const float4 fa = *(const float4*)(p0 + ro);
            const float4 fb4 = *(const float4*)(p1 + ro);
            const float4 fc = *(const float4*)(p2 + ro);
            const float f[12] = {fa.x, fa.y, fa.z, fa.w, fb4.x, fb4.y, fb4.z, fb4.w,
                                 fc.x, fc.y, fc.z, fc.w};
#pragma unroll
            for (int dy = 0; dy < 2; ++dy) {
                const int B = hy - dy;
                if (B < 0 || B > 4) continue;      // folded at compile time
                const float* wr = w + (hz * 5 + B) * 5;
#pragma unroll
                for (int C = 0; C < 5; ++C) {
                    const float wv = wr[C];
#pragma unroll
                    for (int dx = 0; dx < 8; ++dx)
                        acc[dy][dx] = fmaf(f[C + dx], wv, acc[dy][dx]);
                }
            }
        }
    }

    // ---- store 16 outputs ------------------------------------------------
    const int zo = tz + zg;
    const int xo = xg << 3;
#pragma unroll
    for (int dy = 0; dy < 2; ++dy) {
        const int yo = ty + (yg << 1) + dy;
        float* op = yb + (zo << 12) + (yo << 6) + xo;
        float4 o0 = {acc[dy][0], acc[dy][1], acc[dy][2], acc[dy][3]};
        float4 o1 = {acc[dy][4], acc[dy][5], acc[dy][6], acc[dy][7]};
        *(float4*)(op) = o0;
        *(float4*)(op + 4) = o1;
    }
}

// ---------------------------------------------------------------------------
// K3: in-place per-point 96->96 mix + bias as bf16 MFMA GEMM.
// Block = 128 pts.  LDS yt[96][128] with window-ROTATION swizzle:
//   stored window of pt-window w in row r = (w + 4*(r>>3)) & 31.
// Rotation (not XOR) separates quads into disjoint bank halves -> all LDS
// b32 phases at the 2-access/bank structural floor; and since r>>3 is
// constant within each 8-row group, frag reads keep affine addresses
// (imm offsets).  C transposed through the same buffer -> all global stores
// are coalesced dwordx4.
// ---------------------------------------------------------------------------
__global__ __launch_bounds__(256) void ek(float* __restrict__ io,
                                          const unsigned short* __restrict__ Mtt,
                                          const float* __restrict__ bias) {
    __shared__ float yt[96 * 128];              // 49152 B
    const int t = threadIdx.x;
    const long b_off = ((long)blockIdx.y * 96) << 18;
    const int pt0 = blockIdx.x << 7;            // this block's 128 pts

    // ---- stage y[96][128] -> LDS (rotation-swizzled) ---------------------
    {
        const int l32 = t & 31;
        const int r8 = t >> 5;
#pragma unroll
        for (int pass = 0; pass < 12; ++pass) {
            const int fv = r8 + (pass << 3);
            const float4 v = *(const float4*)(io + b_off + ((long)fv << 18) + pt0 + (l32 << 2));
            const int ws = (l32 + ((fv >> 3) << 2)) & 31;
            *(float4*)(yt + (fv << 7) + (ws << 2)) = v;
        }
    }
    __syncthreads();

    const int lane = t & 63;
    const int wv = t >> 6;                     // wave id 0..3
    const int l15 = lane & 15, quad = lane >> 4;
    const int ptl = wv << 5;                   // wave's 32 pts within tile

    // B-frags: B[k=quad*8+j -> fv][n=l15 -> pt].  fv>>3 = 4*ks+quad (j-indep)
    bf16x8 Bf[2][3];
#pragma unroll
    for (int nt = 0; nt < 2; ++nt)
#pragma unroll
        for (int ks = 0; ks < 3; ++ks) {
            const int pt = ptl + nt * 16 + l15;
            const int rot = ((ks << 2) + quad) << 2;
            const int ws = ((pt >> 2) + rot) & 31;
            const int base = ((ks * 32 + quad * 8) << 7) + (ws << 2) + (pt & 3);
#pragma unroll
            for (int j = 0; j < 8; ++j)
                Bf[nt][ks][j] = f2b(yt[base + (j << 7)]);
        }

    // A-frags (16B loads of bf16 Mtt, L1-resident) + MFMA; hold all C in regs
    float cv[6][2][4];
#pragma unroll
    for (int mt = 0; mt < 6; ++mt) {
        bf16x8 Af[3];
#pragma unroll
        for (int ks = 0; ks < 3; ++ks)
            Af[ks] = *(const bf16x8*)(Mtt + (mt * 16 + l15) * 96 + ks * 32 + quad * 8);
#pragma unroll
        for (int nt = 0; nt < 2; ++nt) {
            f32x4 c = {0.f, 0.f, 0.f, 0.f};
#pragma unroll
            for (int ks = 0; ks < 3; ++ks)
                c = __builtin_amdgcn_mfma_f32_16x16x32_bf16(Af[ks], Bf[nt][ks], c, 0, 0, 0);
#pragma unroll
            for (int r = 0; r < 4; ++r) cv[mt][nt][r] = c[r];
        }
    }
    __syncthreads();                            // all B-reads of yt done

    // ---- transpose C through yt: [gw][pt], same rotation swizzle ---------
#pragma unroll
    for (int mt = 0; mt < 6; ++mt) {
        const int rot = (((mt << 1) + (quad >> 1))) << 2;   // 4*(gw>>3), r-indep
        const int gw0 = mt * 16 + quad * 4;
#pragma unroll
        for (int nt = 0; nt < 2; ++nt) {
            const int pt = ptl + nt * 16 + l15;
            const int ws = ((pt >> 2) + rot) & 31;
            const int base = (gw0 << 7) + (ws << 2) + (pt & 3);
#pragma unroll
            for (int r = 0; r < 4; ++r)
                yt[base + (r << 7)] = cv[mt][nt][r];
        }
    }
    __syncthreads();

    // ---- coalesced read-back + bias + dwordx4 stores ---------------------
    {
        const int wl = t & 31;
        const int r8 = t >> 5;
#pragma unroll
        for (int pass = 0; pass < 12; ++pass) {
            const int row = r8 + (pass << 3);           // row>>3 == pass
            const int ws = (wl + (pass << 2)) & 31;
            float4 v = *(const float4*)(yt + (row << 7) + (ws << 2));
            const float bs = bias[row / 12];
            v.x += bs; v.y += bs; v.z += bs; v.w += bs;
            *(float4*)(io + b_off + ((long)row << 18) + pt0 + (wl << 2)) = v;
        }
    }
}

// ---------------------------------------------------------------------------
extern "C" void kernel_launch(void* const* d_in, const int* in_sizes, int n_in,
                              void* d_out, int out_size, void* d_ws, size_t ws_size,
                              hipStream_t stream) {
    const float* x        = (const float*)d_in[0];
    const float* spatial  = (const float*)d_in[1];
    const float* spherical= (const float*)d_in[2];
    const float* bw1 = (const float*)d_in[3];
    const float* bb1 = (const float*)d_in[4];
    const float* bw2 = (const float*)d_in[5];
    const float* bb2 = (const float*)d_in[6];
    const float* bw3 = (const float*)d_in[7];
    const float* fw1 = (const float*)d_in[8];
    const float* fb1 = (const float*)d_in[9];
    const float* fw2 = (const float*)d_in[10];
    const float* fb2 = (const float*)d_in[11];
    const float* fw3 = (const float*)d_in[12];
    const float* bias = (const float*)d_in[13];

    float* sw = (float*)d_ws;                                     // 12000 floats
    unsigned short* Mtt = (unsigned short*)((char*)d_ws + 48128); // 9216 bf16
    float* out = (float*)d_out;          // also conv staging buffer

    hipLaunchKernelGGL(wk, dim3(7), dim3(256), 0, stream,
                       spatial, spherical, bw1, bb1, bw2, bb2, bw3,
                       fw1, fb1, fw2, fb2, fw3, sw, Mtt);
    hipLaunchKernelGGL(ck, dim3(64, 96, 2), dim3(256), 0, stream, x, sw, out);
    hipLaunchKernelGGL(ek, dim3(2048, 2, 1), dim3(256), 0, stream, out, Mtt, bias);
    (void)in_sizes; (void)n_in; (void)out_size; (void)ws_size;
}

// Round 3
// 581.873 us; speedup vs baseline: 1.0710x; 1.0057x over previous
//
#include <hip/hip_runtime.h>
#include <math.h>

#define DEV __device__ __forceinline__

DEV float gelu_exact(float v) {
    return 0.5f * v * (1.0f + erff(v * 0.7071067811865476f));
}

typedef __attribute__((ext_vector_type(8))) short bf16x8;
typedef __attribute__((ext_vector_type(4))) float f32x4;

DEV short f2b(float f) {
    unsigned u = __builtin_bit_cast(unsigned, f);
    unsigned r = (u + 0x7fffu + ((u >> 16) & 1u)) >> 16;
    return (short)r;
}

// ---------------------------------------------------------------------------
// K1: tiny MLPs -> conv weights sw[96][125] (f32) and transposed mix matrix
// Mtt[gw=96][fv=96] in bf16 (so ek's A-frags are single 16B vector loads).
// ---------------------------------------------------------------------------
__global__ __launch_bounds__(256) void wk(
    const float* __restrict__ spatial, const float* __restrict__ spherical,
    const float* __restrict__ bw1, const float* __restrict__ bb1,
    const float* __restrict__ bw2, const float* __restrict__ bb2,
    const float* __restrict__ bw3,
    const float* __restrict__ fw1, const float* __restrict__ fb1,
    const float* __restrict__ fw2, const float* __restrict__ fb2,
    const float* __restrict__ fw3,
    float* __restrict__ sw, unsigned short* __restrict__ Mtt) {
    const int i = blockIdx.x * 256 + threadIdx.x;
    if (i < 1500) {
        const float a = spatial[2 * i], b = spatial[2 * i + 1];
        float ft[14];
        ft[0] = a; ft[1] = b;
        ft[2] = a * a; ft[3] = a * b; ft[4] = b * a; ft[5] = b * b;
#pragma unroll
        for (int k = 0; k < 4; ++k) {
            ft[6 + 2 * k] = ft[2 + k] * a;
            ft[7 + 2 * k] = ft[2 + k] * b;
        }
        float h1[8], h2[8];
#pragma unroll
        for (int j = 0; j < 8; ++j) {
            float s = bb1[j];
#pragma unroll
            for (int k = 0; k < 14; ++k) s = fmaf(bw1[j * 14 + k], ft[k], s);
            h1[j] = gelu_exact(s);
        }
#pragma unroll
        for (int j = 0; j < 8; ++j) {
            float s = bb2[j];
#pragma unroll
            for (int k = 0; k < 8; ++k) s = fmaf(bw2[j * 8 + k], h1[k], s);
            h2[j] = gelu_exact(s);
        }
        const int o = i / 12, v = i % 12;
#pragma unroll
        for (int c = 0; c < 8; ++c) {
            float s = 0.f;
#pragma unroll
            for (int k = 0; k < 8; ++k) s = fmaf(bw3[c * 8 + k], h2[k], s);
            sw[(c * 12 + v) * 125 + o] = s;   // channel ch = cin*12+v, tap o = A*25+B*5+C
        }
    } else if (i < 1644) {
        const int r = i - 1500;
        const float s0 = spherical[r];
        float ft[3];
        ft[0] = s0; ft[1] = s0 * s0; ft[2] = s0 * s0 * s0;
        float h1[8], h2[8];
#pragma unroll
        for (int j = 0; j < 8; ++j) {
            float s = fb1[j];
#pragma unroll
            for (int k = 0; k < 3; ++k) s = fmaf(fw1[j * 3 + k], ft[k], s);
            h1[j] = gelu_exact(s);
        }
#pragma unroll
        for (int j = 0; j < 8; ++j) {
            float s = fb2[j];
#pragma unroll
            for (int k = 0; k < 8; ++k) s = fmaf(fw2[j * 8 + k], h1[k], s);
            h2[j] = gelu_exact(s);
        }
        const int v = r / 12, w = r % 12;     // spherical row = (v, w)
#pragma unroll
        for (int c = 0; c < 64; ++c) {        // c = f*8 + g
            float s = 0.f;
#pragma unroll
            for (int k = 0; k < 8; ++k) s = fmaf(fw3[c * 8 + k], h2[k], s);
            const int f = c >> 3, g = c & 7;
            Mtt[(g * 12 + w) * 96 + f * 12 + v] = (unsigned short)f2b(s);
        }
    }
}

// ---------------------------------------------------------------------------
// K2: depthwise 5x5x5 conv, SAME/zero pad.  Round-0 structure (no LDS,
// shuffle halo, proven 263us @72% occ), but one block = 1 (b, channel PAIR):
// computes ch 2p and 2p+1 and writes y as packed {bf16 lo=2p, hi=2p+1} dwords
// into rows [0..48) of the out buffer -> write bytes halved, ek reads halved.
// Tile 64x8x8; thread tile 4x * 2y * 2z per channel.
// ---------------------------------------------------------------------------
__global__ __launch_bounds__(256) void ck(const float* __restrict__ x,
                                          const float* __restrict__ sw,
                                          unsigned int* __restrict__ yp) {
    const int chp = blockIdx.y, b = blockIdx.z;
    const int ty = (blockIdx.x & 7) << 3;
    const int tz = (blockIdx.x >> 3) << 3;
    const int t = threadIdx.x;
    const int xq = t & 15, x0 = xq << 2;
    const int y0 = ty + (((t >> 4) & 3) << 1);
    const int z0 = tz + ((t >> 6) << 1);       // wave-uniform

    unsigned int pk[2][2][4];

#pragma unroll
    for (int c2 = 0; c2 < 2; ++c2) {
        const int ch = 2 * chp + c2;
        const float* __restrict__ xb = x + ((long)(b * 96 + ch) << 18);
        const float* __restrict__ w = sw + ch * 125;  // uniform -> scalar loads

        float acc[2][2][4];
#pragma unroll
        for (int i = 0; i < 2; ++i)
#pragma unroll
            for (int j = 0; j < 2; ++j)
#pragma unroll
                for (int k = 0; k < 4; ++k) acc[i][j][k] = 0.f;

#pragma unroll
        for (int hz = 0; hz < 6; ++hz) {
            const int zz = z0 + hz - 2;
            if (zz < 0 || zz >= 64) continue;      // wave-uniform branch
#pragma unroll
            for (int hy = 0; hy < 6; ++hy) {
                const int yy = y0 + hy - 2;
                // yy uniform within each 16-lane shuffle group.
                if (yy >= 0 && yy < 64) {
                    const float* row = xb + (zz << 12) + (yy << 6);
                    const float4 v4 = *(const float4*)(row + x0);
                    const float uz = __shfl_up(v4.z, 1, 16);
                    const float uw = __shfl_up(v4.w, 1, 16);
                    const float dx_ = __shfl_down(v4.x, 1, 16);
                    const float dy_ = __shfl_down(v4.y, 1, 16);
                    float f[8];
                    f[0] = (xq > 0) ? uz : 0.f;
                    f[1] = (xq > 0) ? uw : 0.f;
                    f[2] = v4.x; f[3] = v4.y; f[4] = v4.z; f[5] = v4.w;
                    f[6] = (xq < 15) ? dx_ : 0.f;
                    f[7] = (xq < 15) ? dy_ : 0.f;
#pragma unroll
                    for (int dz = 0; dz < 2; ++dz) {
                        const int A = hz - dz;
                        if (A < 0 || A > 4) continue;   // folded at compile time
#pragma unroll
                        for (int dy = 0; dy < 2; ++dy) {
                            const int B = hy - dy;
                            if (B < 0 || B > 4) continue;
                            const float* wr = w + (A * 5 + B) * 5;
#pragma unroll
                            for (int C = 0; C < 5; ++C) {
                                const float wv = wr[C];
#pragma unroll
                                for (int dx = 0; dx < 4; ++dx)
                                    acc[dz][dy][dx] = fmaf(f[C + dx], wv, acc[dz][dy][dx]);
                            }
                        }
                    }
                }
            }
        }
        // pack results as bf16 (same f2b that ek used to apply)
#pragma unroll
        for (int dz = 0; dz < 2; ++dz)
#pragma unroll
            for (int dy = 0; dy < 2; ++dy)
#pragma unroll
                for (int dx = 0; dx < 4; ++dx) {
                    const unsigned int h = (unsigned short)f2b(acc[dz][dy][dx]);
                    if (c2 == 0) pk[dz][dy][dx] = h;
                    else         pk[dz][dy][dx] |= (h << 16);
                }
    }

    unsigned int* yb = yp + ((long)(b * 96 + chp) << 18);
#pragma unroll
    for (int dz = 0; dz < 2; ++dz)
#pragma unroll
        for (int dy = 0; dy < 2; ++dy) {
            uint4 o;
            o.x = pk[dz][dy][0]; o.y = pk[dz][dy][1];
            o.z = pk[dz][dy][2]; o.w = pk[dz][dy][3];
            *(uint4*)(yb + ((z0 + dz) << 12) + ((y0 + dy) << 6) + x0) = o;
        }
}

// ---------------------------------------------------------------------------
// K3: per-point 96->96 mix + bias as bf16 MFMA GEMM, reading PACKED bf16 y
// (rows 0..47 of out buffer) and writing f32 out (rows 0..95), same columns
// -> block-local overlap only, in-place safe.
// Stage: 48 rows x 128 dwords (24 KB) with rotation swizzle
//   dword(pt) of pair-row pr lives at (pr<<7) + ((((pt>>2)+pr)&31)<<2) + (pt&3)
// B-frags = 4 swizzled b32 reads reinterpreted as bf16x8 (zero f2b).
// C transposed through the same 48 KB LDS (rot 2*(gw>>2): verified 2-way floor)
// -> all global I/O is coalesced 16B.
// ---------------------------------------------------------------------------
__global__ __launch_bounds__(256) void ek(float* __restrict__ io,
                                          const unsigned int* __restrict__ yp,
                                          const unsigned short* __restrict__ Mtt,
                                          const float* __restrict__ bias) {
    __shared__ float lds[96 * 128];             // 49152 B (stage uses first 24 KB)
    unsigned int* ldu = (unsigned int*)lds;
    const int t = threadIdx.x;
    const long row0 = (long)blockIdx.y * 96;
    const int pt0 = blockIdx.x << 7;            // this block's 128 pts

    // ---- stage 48 packed rows -> LDS (rotation-swizzled) -----------------
    {
        const int l32 = t & 31, r8 = t >> 5;
#pragma unroll
        for (int pass = 0; pass < 6; ++pass) {
            const int pr = r8 + (pass << 3);
            const uint4 v = *(const uint4*)(yp + ((row0 + pr) << 18) + pt0 + (l32 << 2));
            const int ws = (l32 + pr) & 31;
            *(uint4*)(ldu + (pr << 7) + (ws << 2)) = v;
        }
    }
    __syncthreads();

    const int lane = t & 63;
    const int wv4 = t >> 6;                    // wave id 0..3
    const int l15 = lane & 15, quad = lane >> 4;
    const int ptl = wv4 << 5;                  // wave's 32 pts within tile

    // B-frags: B[k=quad*8+j -> fv][n=l15 -> pt]; fv pair-rows 16ks+4q+jj
    bf16x8 Bf[2][3];
#pragma unroll
    for (int nt = 0; nt < 2; ++nt)
#pragma unroll
        for (int ks = 0; ks < 3; ++ks) {
            const int pt = ptl + nt * 16 + l15;
            const int pr0 = 16 * ks + 4 * quad;
            uint4 d;
            {
                const int b0 = (pt >> 2) + pr0;
                d.x = ldu[((pr0 + 0) << 7) + (((b0 + 0) & 31) << 2) + (pt & 3)];
                d.y = ldu[((pr0 + 1) << 7) + (((b0 + 1) & 31) << 2) + (pt & 3)];
                d.z = ldu[((pr0 + 2) << 7) + (((b0 + 2) & 31) << 2) + (pt & 3)];
                d.w = ldu[((pr0 + 3) << 7) + (((b0 + 3) & 31) << 2) + (pt & 3)];
            }
            Bf[nt][ks] = __builtin_bit_cast(bf16x8, d);
        }

    // A-frags (16B loads of bf16 Mtt, L1-resident) + MFMA; hold all C in regs
    float cv[6][2][4];
#pragma unroll
    for (int mt = 0; mt < 6; ++mt) {
        bf16x8 Af[3];
#pragma unroll
        for (int ks = 0; ks < 3; ++ks)
            Af[ks] = *(const bf16x8*)(Mtt + (mt * 16 + l15) * 96 + ks * 32 + quad * 8);
#pragma unroll
        for (int nt = 0; nt < 2; ++nt) {
            f32x4 c = {0.f, 0.f, 0.f, 0.f};
#pragma unroll
            for (int ks = 0; ks < 3; ++ks)
                c = __builtin_amdgcn_mfma_f32_16x16x32_bf16(Af[ks], Bf[nt][ks], c, 0, 0, 0);
#pragma unroll
            for (int r = 0; r < 4; ++r) cv[mt][nt][r] = c[r];
        }
    }
    __syncthreads();                            // all stage reads of LDS done

    // ---- transpose C through lds: row gw, rot 2*(gw>>2) ------------------
#pragma unroll
    for (int mt = 0; mt < 6; ++mt)
#pragma unroll
        for (int nt = 0; nt < 2; ++nt) {
            const int pt = ptl + nt * 16 + l15;
#pragma unroll
            for (int r = 0; r < 4; ++r) {
                const int gw = mt * 16 + quad * 4 + r;
                const int ws = ((pt >> 2) + 2 * (gw >> 2)) & 31;
                lds[(gw << 7) + (ws << 2) + (pt & 3)] = cv[mt][nt][r];
            }
        }
    __syncthreads();

    // ---- coalesced read-back + bias + dwordx4 stores ---------------------
    {
        const int l32 = t & 31, r8 = t >> 5;
#pragma unroll
        for (int pass = 0; pass < 12; ++pass) {
            const int row = r8 + (pass << 3);
            const int ws = (l32 + 2 * (row >> 2)) & 31;
            float4 v = *(const float4*)(lds + (row << 7) + (ws << 2));
            const float bs = bias[row / 12];
            v.x += bs; v.y += bs; v.z += bs; v.w += bs;
            *(float4*)(io + ((row0 + row) << 18) + pt0 + (l32 << 2)) = v;
        }
    }
}

// ---------------------------------------------------------------------------
extern "C" void kernel_launch(void* const* d_in, const int* in_sizes, int n_in,
                              void* d_out, int out_size, void* d_ws, size_t ws_size,
                              hipStream_t stream) {
    const float* x        = (const float*)d_in[0];
    const float* spatial  = (const float*)d_in[1];
    const float* spherical= (const float*)d_in[2];
    const float* bw1 = (const float*)d_in[3];
    const float* bb1 = (const float*)d_in[4];
    const float* bw2 = (const float*)d_in[5];
    const float* bb2 = (const float*)d_in[6];
    const float* bw3 = (const float*)d_in[7];
    const float* fw1 = (const float*)d_in[8];
    const float* fb1 = (const float*)d_in[9];
    const float* fw2 = (const float*)d_in[10];
    const float* fb2 = (const float*)d_in[11];
    const float* fw3 = (const float*)d_in[12];
    const float* bias = (const float*)d_in[13];

    float* sw = (float*)d_ws;                                     // 12000 floats
    unsigned short* Mtt = (unsigned short*)((char*)d_ws + 48128); // 9216 bf16
    float* out = (float*)d_out;          // rows 0..47: packed bf16 y staging

    hipLaunchKernelGGL(wk, dim3(7), dim3(256), 0, stream,
                       spatial, spherical, bw1, bb1, bw2, bb2, bw3,
                       fw1, fb1, fw2, fb2, fw3, sw, Mtt);
    hipLaunchKernelGGL(ck, dim3(64, 48, 2), dim3(256), 0, stream,
                       x, sw, (unsigned int*)out);
    hipLaunchKernelGGL(ek, dim3(2048, 2, 1), dim3(256), 0, stream,
                       out, (const unsigned int*)out, Mtt, bias);
    (void)in_sizes; (void)n_in; (void)out_size; (void)ws_size;
}